// Round 5
// baseline (200.133 us; speedup 1.0000x reference)
//
#include <hip/hip_runtime.h>
#include <hip/hip_bf16.h>

#define N_NODES 100000
#define N_EDGES 1600000
#define D 128
#define TILES (N_NODES / 16)   // 6250 row-tiles of 16
#define WPB 8                  // waves per block in fused kernel
#define FBLK 391               // fused_k persistent blocks (391*8*2 >= 6250)
#define NBKT 196               // buckets = dst >> 9 (100000/512)
#define NPB 512                // nodes per bucket
#define EPB 8192               // edges per partition block
#define PBLK 196               // ceil(1600000/8192)
#define CVTB 6250              // cvt blocks in fused cvt+p1

typedef __attribute__((ext_vector_type(4))) float f32x4;
typedef __attribute__((ext_vector_type(2))) float f32x2;
typedef __attribute__((ext_vector_type(8))) short short8;
typedef __attribute__((ext_vector_type(4))) unsigned int u32x4;
typedef __attribute__((ext_vector_type(2))) unsigned int u32x2;

// f32 -> bf16 round-to-nearest-even
static __device__ __forceinline__ unsigned short f2bf(float f) {
  unsigned u = __float_as_uint(f);
  u += 0x7fffu + ((u >> 16) & 1u);
  return (unsigned short)(u >> 16);
}

static __device__ __forceinline__ void acc4(u32x2 u, float& a0, float& a1,
                                            float& a2, float& a3) {
  a0 += __uint_as_float(u[0] << 16);
  a1 += __uint_as_float(u[0] & 0xffff0000u);
  a2 += __uint_as_float(u[1] << 16);
  a3 += __uint_as_float(u[1] & 0xffff0000u);
}

// ---- Fused cvt (x->bf16) + p1 (bucket histogram), disjoint block ranges ----
__global__ __launch_bounds__(256) void cvtp1_k(const float* __restrict__ x,
                                               unsigned* __restrict__ xh,
                                               const int* __restrict__ ei,
                                               int* __restrict__ gbcnt) {
  __shared__ int bh[256];
  if (blockIdx.x < CVTB) {
    size_t i = (size_t)blockIdx.x * 256 + threadIdx.x;
    const f32x4* p = (const f32x4*)(x + i * 8);
    f32x4 v0 = p[0], v1 = p[1];
    u32x4 o;
    o[0] = ((unsigned)f2bf(v0[1]) << 16) | f2bf(v0[0]);
    o[1] = ((unsigned)f2bf(v0[3]) << 16) | f2bf(v0[2]);
    o[2] = ((unsigned)f2bf(v1[1]) << 16) | f2bf(v1[0]);
    o[3] = ((unsigned)f2bf(v1[3]) << 16) | f2bf(v1[2]);
    *(u32x4*)(xh + i * 4) = o;
    return;
  }
  int t = threadIdx.x;
  bh[t] = 0;
  __syncthreads();
  int base = (blockIdx.x - CVTB) * EPB;
  int end = min(base + EPB, N_EDGES);
  for (int i = base + t; i < end; i += 256)
    atomicAdd(&bh[ei[N_EDGES + i] >> 9], 1);
  __syncthreads();
  if (t < NBKT && bh[t]) atomicAdd(&gbcnt[t], bh[t]);
}

// ---- P3: partition edges into bucket-contiguous code array ----
// code = (dst & 511) << 17 | src. Bucket bases computed by local LDS scan
// of gbcnt; btail is a zero-initialized per-bucket relative allocator.
__global__ __launch_bounds__(256) void p3_part(const int* __restrict__ ei,
                                               const int* __restrict__ gbcnt,
                                               int* __restrict__ btail,
                                               unsigned* __restrict__ part) {
  __shared__ int sb[256], bh[256], lbase[256], lcur[256];
  int t = threadIdx.x;
  int v = (t < NBKT) ? gbcnt[t] : 0;
  sb[t] = v;
  __syncthreads();
  for (int o = 1; o < 256; o <<= 1) {
    int u = (t >= o) ? sb[t - o] : 0;
    __syncthreads();
    sb[t] += u;
    __syncthreads();
  }
  int myex = sb[t] - v;  // exclusive bucket base
  bh[t] = 0;
  lcur[t] = 0;
  __syncthreads();
  int base = blockIdx.x * EPB;
  int end = min(base + EPB, N_EDGES);
  for (int i = base + t; i < end; i += 256)
    atomicAdd(&bh[ei[N_EDGES + i] >> 9], 1);
  __syncthreads();
  if (t < NBKT && bh[t]) lbase[t] = myex + atomicAdd(&btail[t], bh[t]);
  __syncthreads();
  for (int i = base + t; i < end; i += 256) {
    int dst = ei[N_EDGES + i];
    int src = ei[i];
    int b = dst >> 9;
    int idx = atomicAdd(&lcur[b], 1);
    part[lbase[b] + idx] = ((unsigned)(dst & (NPB - 1)) << 17) | (unsigned)src;
  }
}

// ---- P4: per-bucket CSR build via LDS atomics; bucket range from local scan ----
__global__ __launch_bounds__(512) void p4_build(const unsigned* __restrict__ part,
                                                const int* __restrict__ gbcnt,
                                                int* __restrict__ cnt,
                                                int* __restrict__ ptr,
                                                int* __restrict__ csr) {
  __shared__ int sc[512];
  __shared__ int sw[512];
  __shared__ int s_beg, s_end;
  int t = threadIdx.x, b = blockIdx.x;
  // local inclusive scan of gbcnt (first 256 threads) -> this bucket's range
  if (t < 256) sw[t] = (t < NBKT) ? gbcnt[t] : 0;
  __syncthreads();
  for (int o = 1; o < 256; o <<= 1) {
    int u = (t >= o && t < 256) ? sw[t - o] : 0;
    __syncthreads();
    if (t < 256) sw[t] += u;
    __syncthreads();
  }
  if (t == 0) {
    int g = gbcnt[b];
    s_end = sw[b];
    s_beg = sw[b] - g;
  }
  sc[t] = 0;
  __syncthreads();
  int beg = s_beg, end = s_end;
  for (int i = beg + t; i < end; i += 512) atomicAdd(&sc[part[i] >> 17], 1);
  __syncthreads();
  int my = sc[t];
  for (int o = 1; o < 512; o <<= 1) {  // inclusive scan over node counts
    int u = (t >= o) ? sc[t - o] : 0;
    __syncthreads();
    sc[t] += u;
    __syncthreads();
  }
  int ex = sc[t] - my;
  int node = b * NPB + t;
  if (node < N_NODES) {
    cnt[node] = my;
    ptr[node] = beg + ex;
  }
  sw[t] = ex;
  __syncthreads();
  for (int i = beg + t; i < end; i += 512) {
    unsigned c = part[i];
    int pos = atomicAdd(&sw[c >> 17], 1);
    csr[beg + pos] = (int)(c & 0x1FFFFu);
  }
}

// ---- Gather v3: 2 nodes/wave, 32 lanes x 4 dims, 8-deep MLP ----
__global__ __launch_bounds__(256) void gather2_k(const unsigned* __restrict__ xh,
                                                 const int* __restrict__ csr,
                                                 const int* __restrict__ ptr,
                                                 const int* __restrict__ cnt,
                                                 unsigned* __restrict__ mh) {
  int wid = (blockIdx.x * 256 + threadIdx.x) >> 6;
  int lane = threadIdx.x & 63;
  int half = lane >> 5, lh = lane & 31;
  int node = wid * 2 + half;
  if (node >= N_NODES) return;
  int base = ptr[node];
  int deg = cnt[node];
  float a0 = 0.f, a1 = 0.f, a2 = 0.f, a3 = 0.f;
  float b0 = 0.f, b1 = 0.f, b2 = 0.f, b3 = 0.f;
  for (int c = 0; c < deg; c += 32) {
    int rem = deg - c;
    int n = min(32, rem);
    int eidx = (lh < rem) ? csr[base + c + lh] : 0;
    int j = 0;
    for (; j + 7 < n; j += 8) {
      int s0 = __shfl(eidx, j, 32);
      int s1 = __shfl(eidx, j + 1, 32);
      int s2 = __shfl(eidx, j + 2, 32);
      int s3 = __shfl(eidx, j + 3, 32);
      int s4 = __shfl(eidx, j + 4, 32);
      int s5 = __shfl(eidx, j + 5, 32);
      int s6 = __shfl(eidx, j + 6, 32);
      int s7 = __shfl(eidx, j + 7, 32);
      u32x2 u0 = *(const u32x2*)(xh + (size_t)s0 * 64 + lh * 2);
      u32x2 u1 = *(const u32x2*)(xh + (size_t)s1 * 64 + lh * 2);
      u32x2 u2 = *(const u32x2*)(xh + (size_t)s2 * 64 + lh * 2);
      u32x2 u3 = *(const u32x2*)(xh + (size_t)s3 * 64 + lh * 2);
      u32x2 u4 = *(const u32x2*)(xh + (size_t)s4 * 64 + lh * 2);
      u32x2 u5 = *(const u32x2*)(xh + (size_t)s5 * 64 + lh * 2);
      u32x2 u6 = *(const u32x2*)(xh + (size_t)s6 * 64 + lh * 2);
      u32x2 u7 = *(const u32x2*)(xh + (size_t)s7 * 64 + lh * 2);
      acc4(u0, a0, a1, a2, a3);
      acc4(u1, b0, b1, b2, b3);
      acc4(u2, a0, a1, a2, a3);
      acc4(u3, b0, b1, b2, b3);
      acc4(u4, a0, a1, a2, a3);
      acc4(u5, b0, b1, b2, b3);
      acc4(u6, a0, a1, a2, a3);
      acc4(u7, b0, b1, b2, b3);
    }
    for (; j + 3 < n; j += 4) {
      int s0 = __shfl(eidx, j, 32);
      int s1 = __shfl(eidx, j + 1, 32);
      int s2 = __shfl(eidx, j + 2, 32);
      int s3 = __shfl(eidx, j + 3, 32);
      u32x2 u0 = *(const u32x2*)(xh + (size_t)s0 * 64 + lh * 2);
      u32x2 u1 = *(const u32x2*)(xh + (size_t)s1 * 64 + lh * 2);
      u32x2 u2 = *(const u32x2*)(xh + (size_t)s2 * 64 + lh * 2);
      u32x2 u3 = *(const u32x2*)(xh + (size_t)s3 * 64 + lh * 2);
      acc4(u0, a0, a1, a2, a3);
      acc4(u1, b0, b1, b2, b3);
      acc4(u2, a0, a1, a2, a3);
      acc4(u3, b0, b1, b2, b3);
    }
    for (; j < n; j++) {
      int s0 = __shfl(eidx, j, 32);
      u32x2 u0 = *(const u32x2*)(xh + (size_t)s0 * 64 + lh * 2);
      acc4(u0, a0, a1, a2, a3);
    }
  }
  float inv = 1.0f / fmaxf((float)deg, 1.0f);
  a0 = (a0 + b0) * inv;
  a1 = (a1 + b1) * inv;
  a2 = (a2 + b2) * inv;
  a3 = (a3 + b3) * inv;
  u32x2 o;
  o[0] = ((unsigned)f2bf(a1) << 16) | f2bf(a0);
  o[1] = ((unsigned)f2bf(a3) << 16) | f2bf(a2);
  *(u32x2*)(mh + (size_t)node * 64 + lh * 2) = o;
}

// ---- Fused: out = normalize( [mean | x] @ [W_l; W_r] + b_l ), bf16 MFMA ----
// Persistent grid: W staged once per block, waves grid-stride over row tiles.
__global__ __launch_bounds__(512) void fused_k(
    const unsigned* __restrict__ xh, const unsigned* __restrict__ mh,
    const float* __restrict__ Wl, const float* __restrict__ bl,
    const float* __restrict__ Wr, float* __restrict__ out) {
  __shared__ unsigned short Wt[128 * 256];  // 64 KiB

  int tid = threadIdx.x;
  for (int i = tid; i < 128 * 256; i += 512) {
    int k = i >> 7;       // 0..255 (0..127 = W_l rows, 128..255 = W_r rows)
    int c = i & 127;      // output column
    float w = (k < 128) ? Wl[k * 128 + c] : Wr[(k - 128) * 128 + c];
    int phys = (k >> 3) ^ (c & 7);  // swizzle 16B chunk index within the row
    Wt[c * 256 + (phys << 3) + (k & 7)] = f2bf(w);
  }
  __syncthreads();

  int lane = tid & 63;
  int wid = tid >> 6;
  int c0 = lane & 15;  // A-row within tile / D-column-within-16
  int g = lane >> 4;   // k-group selector

  for (int tile = blockIdx.x * WPB + wid; tile < TILES; tile += FBLK * WPB) {
    int row0 = tile * 16;

    f32x4 acc[8];
    #pragma unroll
    for (int ct = 0; ct < 8; ct++)
      for (int j = 0; j < 4; j++) acc[ct][j] = 0.0f;

    #pragma unroll
    for (int kf = 0; kf < 8; kf++) {
      int koff = (kf & 3) * 32 + g * 8;
      const unsigned short* a_src =
          (const unsigned short*)((kf < 4) ? mh : xh);
      short8 af = *(const short8*)(a_src + (size_t)(row0 + c0) * D + koff);
      #pragma unroll
      for (int ct = 0; ct < 8; ct++) {
        int c = ct * 16 + c0;
        short8 bf = *(const short8*)&Wt[c * 256 + ((((kf << 2) + g) ^ (c & 7)) << 3)];
        acc[ct] = __builtin_amdgcn_mfma_f32_16x16x32_bf16(af, bf, acc[ct], 0, 0, 0);
      }
    }

    // Epilogue: + bias, row L2-normalize (D layout: col = lane&15, row = g*4+j).
    float ss[4] = {0.f, 0.f, 0.f, 0.f};
    #pragma unroll
    for (int ct = 0; ct < 8; ct++) {
      float bias = bl[ct * 16 + c0];
      #pragma unroll
      for (int j = 0; j < 4; j++) {
        float v = acc[ct][j] + bias;
        acc[ct][j] = v;
        ss[j] += v * v;
      }
    }
    #pragma unroll
    for (int j = 0; j < 4; j++) {
      float s = ss[j];
      s += __shfl_xor(s, 1);
      s += __shfl_xor(s, 2);
      s += __shfl_xor(s, 4);
      s += __shfl_xor(s, 8);
      ss[j] = 1.0f / fmaxf(sqrtf(s), 1e-12f);
    }
    #pragma unroll
    for (int ct = 0; ct < 8; ct++) {
      #pragma unroll
      for (int j = 0; j < 4; j++) {
        out[(size_t)(row0 + g * 4 + j) * D + ct * 16 + c0] = acc[ct][j] * ss[j];
      }
    }
  }
}

extern "C" void kernel_launch(void* const* d_in, const int* in_sizes, int n_in,
                              void* d_out, int out_size, void* d_ws, size_t ws_size,
                              hipStream_t stream) {
  const float* x  = (const float*)d_in[0];
  const int*   ei = (const int*)d_in[1];
  const float* Wl = (const float*)d_in[2];
  const float* bl = (const float*)d_in[3];
  const float* Wr = (const float*)d_in[4];
  float* out = (float*)d_out;

  // Workspace layout (int elements)
  int* w = (int*)d_ws;
  int* cnt   = w;                      // 100000
  int* ptr   = w + 100000;             // 100000
  int* gbcnt = w + 200000;             // 256
  int* btail = w + 200256;             // 256 (contiguous with gbcnt for memset)
  unsigned* part = (unsigned*)(w + 200512);  // 1600000
  int* csr   = w + 1800512;            // 1600000
  const size_t XH_OFF = 3400512ULL * 4;       // bytes, 16B aligned
  const size_t MH_OFF = XH_OFF + (size_t)N_NODES * D * 2;  // +25.6 MB
  unsigned* xh = (unsigned*)((char*)d_ws + XH_OFF);
  unsigned* mh = (unsigned*)((char*)d_ws + MH_OFF);

  hipMemsetAsync(gbcnt, 0, 512 * sizeof(int), stream);
  cvtp1_k<<<CVTB + PBLK, 256, 0, stream>>>(x, xh, ei, gbcnt);
  p3_part<<<PBLK, 256, 0, stream>>>(ei, gbcnt, btail, part);
  p4_build<<<NBKT, 512, 0, stream>>>(part, gbcnt, cnt, ptr, csr);
  gather2_k<<<12500, 256, 0, stream>>>(xh, csr, ptr, cnt, mh);
  fused_k<<<FBLK, 512, 0, stream>>>(xh, mh, Wl, bl, Wr, out);
}

// Round 7
// 149.057 us; speedup vs baseline: 1.3427x; 1.3427x over previous
//
#include <hip/hip_runtime.h>
#include <hip/hip_bf16.h>

#define N_NODES 100000
#define N_EDGES 1600000
#define D 128
#define TILES (N_NODES / 16)   // 6250 row-tiles of 16
#define WPB 8                  // waves per block in fused kernel
#define NBKT 196               // buckets = dst >> 9 (100000/512)
#define NPB 512                // nodes per bucket
#define EPB 8192               // edges per partition block
#define PBLK 196               // ceil(1600000/8192)
#define CVTB 6250              // cvt blocks in fused cvt+p1

typedef __attribute__((ext_vector_type(4))) float f32x4;
typedef __attribute__((ext_vector_type(8))) short short8;
typedef __attribute__((ext_vector_type(4))) unsigned int u32x4;
typedef __attribute__((ext_vector_type(2))) unsigned int u32x2;

// f32 -> bf16 round-to-nearest-even
static __device__ __forceinline__ unsigned short f2bf(float f) {
  unsigned u = __float_as_uint(f);
  u += 0x7fffu + ((u >> 16) & 1u);
  return (unsigned short)(u >> 16);
}

static __device__ __forceinline__ void acc4(u32x2 u, float& a0, float& a1,
                                            float& a2, float& a3) {
  a0 += __uint_as_float(u[0] << 16);
  a1 += __uint_as_float(u[0] & 0xffff0000u);
  a2 += __uint_as_float(u[1] << 16);
  a3 += __uint_as_float(u[1] & 0xffff0000u);
}

// ---- Prep: W -> bf16 in the exact physical (swizzled) LDS layout ----
// phys layout: wt_g[c*256 + (((k>>3)^(c&7))<<3) + (k&7)], c=out col, k=0..255
__global__ __launch_bounds__(256) void prepw_k(const float* __restrict__ Wl,
                                               const float* __restrict__ Wr,
                                               unsigned short* __restrict__ wt_g) {
  int i = blockIdx.x * 256 + threadIdx.x;  // 0..32767
  int k = i >> 7, c = i & 127;
  float w = (k < 128) ? Wl[k * 128 + c] : Wr[(k - 128) * 128 + c];
  int phys = (k >> 3) ^ (c & 7);
  wt_g[c * 256 + (phys << 3) + (k & 7)] = f2bf(w);
}

// ---- Fused cvt (x->bf16) + p1 (bucket histogram), disjoint block ranges ----
__global__ __launch_bounds__(256) void cvtp1_k(const float* __restrict__ x,
                                               unsigned* __restrict__ xh,
                                               const int* __restrict__ ei,
                                               int* __restrict__ gbcnt) {
  __shared__ int bh[256];
  if (blockIdx.x < CVTB) {
    size_t i = (size_t)blockIdx.x * 256 + threadIdx.x;
    const f32x4* p = (const f32x4*)(x + i * 8);
    f32x4 v0 = p[0], v1 = p[1];
    u32x4 o;
    o[0] = ((unsigned)f2bf(v0[1]) << 16) | f2bf(v0[0]);
    o[1] = ((unsigned)f2bf(v0[3]) << 16) | f2bf(v0[2]);
    o[2] = ((unsigned)f2bf(v1[1]) << 16) | f2bf(v1[0]);
    o[3] = ((unsigned)f2bf(v1[3]) << 16) | f2bf(v1[2]);
    *(u32x4*)(xh + i * 4) = o;
    return;
  }
  int t = threadIdx.x;
  bh[t] = 0;
  __syncthreads();
  int base = (blockIdx.x - CVTB) * EPB;
  int end = min(base + EPB, N_EDGES);
  for (int i = base + t; i < end; i += 256)
    atomicAdd(&bh[ei[N_EDGES + i] >> 9], 1);
  __syncthreads();
  if (t < NBKT && bh[t]) atomicAdd(&gbcnt[t], bh[t]);
}

// ---- P3: partition edges into bucket-contiguous code array ----
__global__ __launch_bounds__(256) void p3_part(const int* __restrict__ ei,
                                               const int* __restrict__ gbcnt,
                                               int* __restrict__ btail,
                                               unsigned* __restrict__ part) {
  __shared__ int sb[256], bh[256], lbase[256], lcur[256];
  int t = threadIdx.x;
  int v = (t < NBKT) ? gbcnt[t] : 0;
  sb[t] = v;
  __syncthreads();
  for (int o = 1; o < 256; o <<= 1) {
    int u = (t >= o) ? sb[t - o] : 0;
    __syncthreads();
    sb[t] += u;
    __syncthreads();
  }
  int myex = sb[t] - v;  // exclusive bucket base
  bh[t] = 0;
  lcur[t] = 0;
  __syncthreads();
  int base = blockIdx.x * EPB;
  int end = min(base + EPB, N_EDGES);
  for (int i = base + t; i < end; i += 256)
    atomicAdd(&bh[ei[N_EDGES + i] >> 9], 1);
  __syncthreads();
  if (t < NBKT && bh[t]) lbase[t] = myex + atomicAdd(&btail[t], bh[t]);
  __syncthreads();
  for (int i = base + t; i < end; i += 256) {
    int dst = ei[N_EDGES + i];
    int src = ei[i];
    int b = dst >> 9;
    int idx = atomicAdd(&lcur[b], 1);
    part[lbase[b] + idx] = ((unsigned)(dst & (NPB - 1)) << 17) | (unsigned)src;
  }
}

// ---- P4: per-bucket CSR build via LDS atomics ----
__global__ __launch_bounds__(512) void p4_build(const unsigned* __restrict__ part,
                                                const int* __restrict__ gbcnt,
                                                int* __restrict__ cnt,
                                                int* __restrict__ ptr,
                                                int* __restrict__ csr) {
  __shared__ int sc[512];
  __shared__ int sw[512];
  __shared__ int s_beg, s_end;
  int t = threadIdx.x, b = blockIdx.x;
  if (t < 256) sw[t] = (t < NBKT) ? gbcnt[t] : 0;
  __syncthreads();
  for (int o = 1; o < 256; o <<= 1) {
    int u = (t >= o && t < 256) ? sw[t - o] : 0;
    __syncthreads();
    if (t < 256) sw[t] += u;
    __syncthreads();
  }
  if (t == 0) {
    int g = gbcnt[b];
    s_end = sw[b];
    s_beg = sw[b] - g;
  }
  sc[t] = 0;
  __syncthreads();
  int beg = s_beg, end = s_end;
  for (int i = beg + t; i < end; i += 512) atomicAdd(&sc[part[i] >> 17], 1);
  __syncthreads();
  int my = sc[t];
  for (int o = 1; o < 512; o <<= 1) {
    int u = (t >= o) ? sc[t - o] : 0;
    __syncthreads();
    sc[t] += u;
    __syncthreads();
  }
  int ex = sc[t] - my;
  int node = b * NPB + t;
  if (node < N_NODES) {
    cnt[node] = my;
    ptr[node] = beg + ex;
  }
  sw[t] = ex;
  __syncthreads();
  for (int i = beg + t; i < end; i += 512) {
    unsigned c = part[i];
    int pos = atomicAdd(&sw[c >> 17], 1);
    csr[beg + pos] = (int)(c & 0x1FFFFu);
  }
}

// ---- Gather: 2 nodes/wave, 32 lanes x 4 dims, 8-deep MLP ----
__global__ __launch_bounds__(256) void gather2_k(const unsigned* __restrict__ xh,
                                                 const int* __restrict__ csr,
                                                 const int* __restrict__ ptr,
                                                 const int* __restrict__ cnt,
                                                 unsigned* __restrict__ mh) {
  int wid = (blockIdx.x * 256 + threadIdx.x) >> 6;
  int lane = threadIdx.x & 63;
  int half = lane >> 5, lh = lane & 31;
  int node = wid * 2 + half;
  if (node >= N_NODES) return;
  int base = ptr[node];
  int deg = cnt[node];
  float a0 = 0.f, a1 = 0.f, a2 = 0.f, a3 = 0.f;
  float b0 = 0.f, b1 = 0.f, b2 = 0.f, b3 = 0.f;
  for (int c = 0; c < deg; c += 32) {
    int rem = deg - c;
    int n = min(32, rem);
    int eidx = (lh < rem) ? csr[base + c + lh] : 0;
    int j = 0;
    for (; j + 7 < n; j += 8) {
      int s0 = __shfl(eidx, j, 32);
      int s1 = __shfl(eidx, j + 1, 32);
      int s2 = __shfl(eidx, j + 2, 32);
      int s3 = __shfl(eidx, j + 3, 32);
      int s4 = __shfl(eidx, j + 4, 32);
      int s5 = __shfl(eidx, j + 5, 32);
      int s6 = __shfl(eidx, j + 6, 32);
      int s7 = __shfl(eidx, j + 7, 32);
      u32x2 u0 = *(const u32x2*)(xh + (size_t)s0 * 64 + lh * 2);
      u32x2 u1 = *(const u32x2*)(xh + (size_t)s1 * 64 + lh * 2);
      u32x2 u2 = *(const u32x2*)(xh + (size_t)s2 * 64 + lh * 2);
      u32x2 u3 = *(const u32x2*)(xh + (size_t)s3 * 64 + lh * 2);
      u32x2 u4 = *(const u32x2*)(xh + (size_t)s4 * 64 + lh * 2);
      u32x2 u5 = *(const u32x2*)(xh + (size_t)s5 * 64 + lh * 2);
      u32x2 u6 = *(const u32x2*)(xh + (size_t)s6 * 64 + lh * 2);
      u32x2 u7 = *(const u32x2*)(xh + (size_t)s7 * 64 + lh * 2);
      acc4(u0, a0, a1, a2, a3);
      acc4(u1, b0, b1, b2, b3);
      acc4(u2, a0, a1, a2, a3);
      acc4(u3, b0, b1, b2, b3);
      acc4(u4, a0, a1, a2, a3);
      acc4(u5, b0, b1, b2, b3);
      acc4(u6, a0, a1, a2, a3);
      acc4(u7, b0, b1, b2, b3);
    }
    for (; j + 3 < n; j += 4) {
      int s0 = __shfl(eidx, j, 32);
      int s1 = __shfl(eidx, j + 1, 32);
      int s2 = __shfl(eidx, j + 2, 32);
      int s3 = __shfl(eidx, j + 3, 32);
      u32x2 u0 = *(const u32x2*)(xh + (size_t)s0 * 64 + lh * 2);
      u32x2 u1 = *(const u32x2*)(xh + (size_t)s1 * 64 + lh * 2);
      u32x2 u2 = *(const u32x2*)(xh + (size_t)s2 * 64 + lh * 2);
      u32x2 u3 = *(const u32x2*)(xh + (size_t)s3 * 64 + lh * 2);
      acc4(u0, a0, a1, a2, a3);
      acc4(u1, b0, b1, b2, b3);
      acc4(u2, a0, a1, a2, a3);
      acc4(u3, b0, b1, b2, b3);
    }
    for (; j < n; j++) {
      int s0 = __shfl(eidx, j, 32);
      u32x2 u0 = *(const u32x2*)(xh + (size_t)s0 * 64 + lh * 2);
      acc4(u0, a0, a1, a2, a3);
    }
  }
  float inv = 1.0f / fmaxf((float)deg, 1.0f);
  a0 = (a0 + b0) * inv;
  a1 = (a1 + b1) * inv;
  a2 = (a2 + b2) * inv;
  a3 = (a3 + b3) * inv;
  u32x2 o;
  o[0] = ((unsigned)f2bf(a1) << 16) | f2bf(a0);
  o[1] = ((unsigned)f2bf(a3) << 16) | f2bf(a2);
  *(u32x2*)(mh + (size_t)node * 64 + lh * 2) = o;
}

// ---- Fused: out = normalize( [mean | x] @ [W_l; W_r] + b_l ), bf16 MFMA ----
// 1 tile/wave (782 blocks x 8 waves); W staged via 8 linear 16B copies from
// the pre-swizzled wt_g (no converts, conflict-free ds_write_b128).
__global__ __launch_bounds__(512) void fused_k(
    const unsigned* __restrict__ xh, const unsigned* __restrict__ mh,
    const unsigned* __restrict__ wt_g, const float* __restrict__ bl,
    float* __restrict__ out) {
  __shared__ unsigned Wt[16384];  // 64 KiB as u32 (32768 bf16)

  int tid = threadIdx.x;
  {
    const u32x4* src = (const u32x4*)wt_g;
    u32x4* dst = (u32x4*)Wt;
    #pragma unroll
    for (int it = 0; it < 8; it++) dst[it * 512 + tid] = src[it * 512 + tid];
  }
  __syncthreads();

  int tile = blockIdx.x * WPB + (tid >> 6);
  if (tile >= TILES) return;
  int lane = tid & 63;
  int c0 = lane & 15;  // A-row within tile / D-column-within-16
  int g = lane >> 4;   // k-group selector
  int row0 = tile * 16;
  const unsigned short* Wt16 = (const unsigned short*)Wt;

  f32x4 acc[8];
  #pragma unroll
  for (int ct = 0; ct < 8; ct++)
    for (int j = 0; j < 4; j++) acc[ct][j] = 0.0f;

  #pragma unroll
  for (int kf = 0; kf < 8; kf++) {
    int koff = (kf & 3) * 32 + g * 8;
    const unsigned short* a_src = (const unsigned short*)((kf < 4) ? mh : xh);
    short8 af = *(const short8*)(a_src + (size_t)(row0 + c0) * D + koff);
    #pragma unroll
    for (int ct = 0; ct < 8; ct++) {
      int c = ct * 16 + c0;
      short8 bf = *(const short8*)&Wt16[c * 256 + ((((kf << 2) + g) ^ (c & 7)) << 3)];
      acc[ct] = __builtin_amdgcn_mfma_f32_16x16x32_bf16(af, bf, acc[ct], 0, 0, 0);
    }
  }

  // Epilogue: + bias, row L2-normalize (D layout: col = lane&15, row = g*4+j).
  float ss[4] = {0.f, 0.f, 0.f, 0.f};
  #pragma unroll
  for (int ct = 0; ct < 8; ct++) {
    float bias = bl[ct * 16 + c0];
    #pragma unroll
    for (int j = 0; j < 4; j++) {
      float v = acc[ct][j] + bias;
      acc[ct][j] = v;
      ss[j] += v * v;
    }
  }
  #pragma unroll
  for (int j = 0; j < 4; j++) {
    float s = ss[j];
    s += __shfl_xor(s, 1);
    s += __shfl_xor(s, 2);
    s += __shfl_xor(s, 4);
    s += __shfl_xor(s, 8);
    ss[j] = 1.0f / fmaxf(sqrtf(s), 1e-12f);
  }
  #pragma unroll
  for (int ct = 0; ct < 8; ct++) {
    #pragma unroll
    for (int j = 0; j < 4; j++) {
      out[(size_t)(row0 + g * 4 + j) * D + ct * 16 + c0] = acc[ct][j] * ss[j];
    }
  }
}

extern "C" void kernel_launch(void* const* d_in, const int* in_sizes, int n_in,
                              void* d_out, int out_size, void* d_ws, size_t ws_size,
                              hipStream_t stream) {
  const float* x  = (const float*)d_in[0];
  const int*   ei = (const int*)d_in[1];
  const float* Wl = (const float*)d_in[2];
  const float* bl = (const float*)d_in[3];
  const float* Wr = (const float*)d_in[4];
  float* out = (float*)d_out;

  // Workspace layout (int elements)
  int* w = (int*)d_ws;
  int* cnt   = w;                      // 100000
  int* ptr   = w + 100000;             // 100000
  int* gbcnt = w + 200000;             // 256
  int* btail = w + 200256;             // 256 (contiguous with gbcnt for memset)
  unsigned* part = (unsigned*)(w + 200512);  // 1600000
  int* csr   = w + 1800512;            // 1600000
  unsigned short* wt_g = (unsigned short*)(w + 3400512);  // 32768 u16 = 16384 ints
  const size_t XH_OFF = 3416896ULL * 4;       // bytes, 16B aligned
  const size_t MH_OFF = XH_OFF + (size_t)N_NODES * D * 2;  // +25.6 MB
  unsigned* xh = (unsigned*)((char*)d_ws + XH_OFF);
  unsigned* mh = (unsigned*)((char*)d_ws + MH_OFF);

  hipMemsetAsync(gbcnt, 0, 512 * sizeof(int), stream);
  prepw_k<<<128, 256, 0, stream>>>(Wl, Wr, wt_g);
  cvtp1_k<<<CVTB + PBLK, 256, 0, stream>>>(x, xh, ei, gbcnt);
  p3_part<<<PBLK, 256, 0, stream>>>(ei, gbcnt, btail, part);
  p4_build<<<NBKT, 512, 0, stream>>>(part, gbcnt, cnt, ptr, csr);
  gather2_k<<<12500, 256, 0, stream>>>(xh, csr, ptr, cnt, mh);
  fused_k<<<(TILES + WPB - 1) / WPB, 512, 0, stream>>>(xh, mh, (const unsigned*)wt_g, bl, out);
}

// Round 8
// 147.726 us; speedup vs baseline: 1.3548x; 1.0090x over previous
//
#include <hip/hip_runtime.h>
#include <hip/hip_bf16.h>

#define N_NODES 100000
#define N_EDGES 1600000
#define D 128
#define TILES (N_NODES / 16)   // 6250 row-tiles of 16
#define WPB 8                  // waves per block in fused kernel
#define NB2 782                // buckets of 128 nodes (ceil(100000/128))
#define NPB2 128               // nodes per bucket
#define CAP 4096               // edge capacity per bucket (mean 2046, sigma 45)
#define EPB 8192               // edges per partition block
#define PBLK 196               // ceil(1600000/8192)

typedef __attribute__((ext_vector_type(4))) float f32x4;
typedef __attribute__((ext_vector_type(8))) short short8;
typedef __attribute__((ext_vector_type(4))) unsigned int u32x4;
typedef __attribute__((ext_vector_type(2))) unsigned int u32x2;

// f32 -> bf16 round-to-nearest-even
static __device__ __forceinline__ unsigned short f2bf(float f) {
  unsigned u = __float_as_uint(f);
  u += 0x7fffu + ((u >> 16) & 1u);
  return (unsigned short)(u >> 16);
}

static __device__ __forceinline__ void acc4(u32x2 u, float& a0, float& a1,
                                            float& a2, float& a3) {
  a0 += __uint_as_float(u[0] << 16);
  a1 += __uint_as_float(u[0] & 0xffff0000u);
  a2 += __uint_as_float(u[1] << 16);
  a3 += __uint_as_float(u[1] & 0xffff0000u);
}

// ---- Prep: W -> bf16 in the exact physical (swizzled) LDS layout ----
__global__ __launch_bounds__(256) void prepw_k(const float* __restrict__ Wl,
                                               const float* __restrict__ Wr,
                                               unsigned short* __restrict__ wt_g) {
  int i = blockIdx.x * 256 + threadIdx.x;  // 0..32767
  int k = i >> 7, c = i & 127;
  float w = (k < 128) ? Wl[k * 128 + c] : Wr[(k - 128) * 128 + c];
  int phys = (k >> 3) ^ (c & 7);
  wt_g[c * 256 + (phys << 3) + (k & 7)] = f2bf(w);
}

// ---- x -> bf16 (pure convert) ----
__global__ __launch_bounds__(256) void cvt_k(const float* __restrict__ x,
                                             unsigned* __restrict__ xh) {
  size_t i = (size_t)blockIdx.x * 256 + threadIdx.x;
  const f32x4* p = (const f32x4*)(x + i * 8);
  f32x4 v0 = p[0], v1 = p[1];
  u32x4 o;
  o[0] = ((unsigned)f2bf(v0[1]) << 16) | f2bf(v0[0]);
  o[1] = ((unsigned)f2bf(v0[3]) << 16) | f2bf(v0[2]);
  o[2] = ((unsigned)f2bf(v1[1]) << 16) | f2bf(v1[0]);
  o[3] = ((unsigned)f2bf(v1[3]) << 16) | f2bf(v1[2]);
  *(u32x4*)(xh + i * 4) = o;
}

// ---- P3b: partition edges into fixed-cap bucket regions (no pre-count) ----
// code = (dst & 127) << 17 | src  (24 bits)
__global__ __launch_bounds__(256) void p3b_k(const int* __restrict__ ei,
                                             int* __restrict__ btail,
                                             unsigned* __restrict__ part) {
  __shared__ int bh[NB2], lbase[NB2], lcur[NB2];
  int t = threadIdx.x;
  for (int i = t; i < NB2; i += 256) { bh[i] = 0; lcur[i] = 0; }
  __syncthreads();
  int base = blockIdx.x * EPB;
  int end = min(base + EPB, N_EDGES);
  for (int i = base + t; i < end; i += 256)
    atomicAdd(&bh[ei[N_EDGES + i] >> 7], 1);
  __syncthreads();
  for (int i = t; i < NB2; i += 256)
    if (bh[i]) lbase[i] = atomicAdd(&btail[i], bh[i]);
  __syncthreads();
  for (int i = base + t; i < end; i += 256) {
    int dst = ei[N_EDGES + i];
    int src = ei[i];
    int b = dst >> 7;
    int pos = lbase[b] + atomicAdd(&lcur[b], 1);
    if (pos < CAP)
      part[(size_t)b * CAP + pos] =
          ((unsigned)(dst & (NPB2 - 1)) << 17) | (unsigned)src;
  }
}

// ---- G3: per-bucket fused CSR-build (in LDS) + gather + bf16 mean ----
__global__ __launch_bounds__(512) void g3_k(const unsigned* __restrict__ xh,
                                            const unsigned* __restrict__ part,
                                            const int* __restrict__ btail,
                                            unsigned* __restrict__ mh) {
  __shared__ int s_deg[NPB2], s_ptr[NPB2], s_off[NPB2];
  __shared__ int s_csr[CAP];
  int t = threadIdx.x, b = blockIdx.x;
  int ne = min(btail[b], CAP);
  if (t < NPB2) s_deg[t] = 0;
  __syncthreads();
  const unsigned* pp = part + (size_t)b * CAP;
  for (int i = t; i < ne; i += 512) atomicAdd(&s_deg[pp[i] >> 17], 1);
  __syncthreads();
  if (t < NPB2) s_ptr[t] = s_deg[t];
  __syncthreads();
  for (int o = 1; o < NPB2; o <<= 1) {  // inclusive scan over 128 counts
    int u = (t >= o && t < NPB2) ? s_ptr[t - o] : 0;
    __syncthreads();
    if (t < NPB2) s_ptr[t] += u;
    __syncthreads();
  }
  if (t < NPB2) {
    int ex = s_ptr[t] - s_deg[t];
    s_ptr[t] = ex;
    s_off[t] = ex;
  }
  __syncthreads();
  for (int i = t; i < ne; i += 512) {
    unsigned c = pp[i];
    int pos = atomicAdd(&s_off[c >> 17], 1);
    s_csr[pos] = (int)(c & 0x1FFFFu);
  }
  __syncthreads();

  int wv = t >> 6, lane = t & 63, half = lane >> 5, lh = lane & 31;
  for (int p = 0; p < 8; p++) {
    int nl = (wv * 8 + p) * 2 + half;  // local node 0..127
    int node = b * NPB2 + nl;
    bool valid = node < N_NODES;
    int deg = valid ? s_deg[nl] : 0;
    int bse = valid ? s_ptr[nl] : 0;
    float a0 = 0.f, a1 = 0.f, a2 = 0.f, a3 = 0.f;
    float b0 = 0.f, b1 = 0.f, b2 = 0.f, b3 = 0.f;
    for (int c = 0; c < deg; c += 32) {
      int rem = deg - c;
      int n = min(32, rem);
      int eidx = (lh < rem) ? s_csr[bse + c + lh] : 0;
      int j = 0;
      for (; j + 7 < n; j += 8) {
        int s0 = __shfl(eidx, j, 32);
        int s1 = __shfl(eidx, j + 1, 32);
        int s2 = __shfl(eidx, j + 2, 32);
        int s3 = __shfl(eidx, j + 3, 32);
        int s4 = __shfl(eidx, j + 4, 32);
        int s5 = __shfl(eidx, j + 5, 32);
        int s6 = __shfl(eidx, j + 6, 32);
        int s7 = __shfl(eidx, j + 7, 32);
        u32x2 u0 = *(const u32x2*)(xh + (size_t)s0 * 64 + lh * 2);
        u32x2 u1 = *(const u32x2*)(xh + (size_t)s1 * 64 + lh * 2);
        u32x2 u2 = *(const u32x2*)(xh + (size_t)s2 * 64 + lh * 2);
        u32x2 u3 = *(const u32x2*)(xh + (size_t)s3 * 64 + lh * 2);
        u32x2 u4 = *(const u32x2*)(xh + (size_t)s4 * 64 + lh * 2);
        u32x2 u5 = *(const u32x2*)(xh + (size_t)s5 * 64 + lh * 2);
        u32x2 u6 = *(const u32x2*)(xh + (size_t)s6 * 64 + lh * 2);
        u32x2 u7 = *(const u32x2*)(xh + (size_t)s7 * 64 + lh * 2);
        acc4(u0, a0, a1, a2, a3);
        acc4(u1, b0, b1, b2, b3);
        acc4(u2, a0, a1, a2, a3);
        acc4(u3, b0, b1, b2, b3);
        acc4(u4, a0, a1, a2, a3);
        acc4(u5, b0, b1, b2, b3);
        acc4(u6, a0, a1, a2, a3);
        acc4(u7, b0, b1, b2, b3);
      }
      for (; j + 3 < n; j += 4) {
        int s0 = __shfl(eidx, j, 32);
        int s1 = __shfl(eidx, j + 1, 32);
        int s2 = __shfl(eidx, j + 2, 32);
        int s3 = __shfl(eidx, j + 3, 32);
        u32x2 u0 = *(const u32x2*)(xh + (size_t)s0 * 64 + lh * 2);
        u32x2 u1 = *(const u32x2*)(xh + (size_t)s1 * 64 + lh * 2);
        u32x2 u2 = *(const u32x2*)(xh + (size_t)s2 * 64 + lh * 2);
        u32x2 u3 = *(const u32x2*)(xh + (size_t)s3 * 64 + lh * 2);
        acc4(u0, a0, a1, a2, a3);
        acc4(u1, b0, b1, b2, b3);
        acc4(u2, a0, a1, a2, a3);
        acc4(u3, b0, b1, b2, b3);
      }
      for (; j < n; j++) {
        int s0 = __shfl(eidx, j, 32);
        u32x2 u0 = *(const u32x2*)(xh + (size_t)s0 * 64 + lh * 2);
        acc4(u0, a0, a1, a2, a3);
      }
    }
    if (valid) {
      float inv = 1.0f / fmaxf((float)deg, 1.0f);
      a0 = (a0 + b0) * inv;
      a1 = (a1 + b1) * inv;
      a2 = (a2 + b2) * inv;
      a3 = (a3 + b3) * inv;
      u32x2 o;
      o[0] = ((unsigned)f2bf(a1) << 16) | f2bf(a0);
      o[1] = ((unsigned)f2bf(a3) << 16) | f2bf(a2);
      *(u32x2*)(mh + (size_t)node * 64 + lh * 2) = o;
    }
  }
}

// ---- Fused: out = normalize( [mean | x] @ [W_l; W_r] + b_l ), bf16 MFMA ----
__global__ __launch_bounds__(512) void fused_k(
    const unsigned* __restrict__ xh, const unsigned* __restrict__ mh,
    const unsigned* __restrict__ wt_g, const float* __restrict__ bl,
    float* __restrict__ out) {
  __shared__ unsigned Wt[16384];  // 64 KiB as u32 (32768 bf16)

  int tid = threadIdx.x;
  {
    const u32x4* src = (const u32x4*)wt_g;
    u32x4* dst = (u32x4*)Wt;
    #pragma unroll
    for (int it = 0; it < 8; it++) dst[it * 512 + tid] = src[it * 512 + tid];
  }
  __syncthreads();

  int tile = blockIdx.x * WPB + (tid >> 6);
  if (tile >= TILES) return;
  int lane = tid & 63;
  int c0 = lane & 15;  // A-row within tile / D-column-within-16
  int g = lane >> 4;   // k-group selector
  int row0 = tile * 16;
  const unsigned short* Wt16 = (const unsigned short*)Wt;

  f32x4 acc[8];
  #pragma unroll
  for (int ct = 0; ct < 8; ct++)
    for (int j = 0; j < 4; j++) acc[ct][j] = 0.0f;

  #pragma unroll
  for (int kf = 0; kf < 8; kf++) {
    int koff = (kf & 3) * 32 + g * 8;
    const unsigned short* a_src = (const unsigned short*)((kf < 4) ? mh : xh);
    short8 af = *(const short8*)(a_src + (size_t)(row0 + c0) * D + koff);
    #pragma unroll
    for (int ct = 0; ct < 8; ct++) {
      int c = ct * 16 + c0;
      short8 bf = *(const short8*)&Wt16[c * 256 + ((((kf << 2) + g) ^ (c & 7)) << 3)];
      acc[ct] = __builtin_amdgcn_mfma_f32_16x16x32_bf16(af, bf, acc[ct], 0, 0, 0);
    }
  }

  float ss[4] = {0.f, 0.f, 0.f, 0.f};
  #pragma unroll
  for (int ct = 0; ct < 8; ct++) {
    float bias = bl[ct * 16 + c0];
    #pragma unroll
    for (int j = 0; j < 4; j++) {
      float v = acc[ct][j] + bias;
      acc[ct][j] = v;
      ss[j] += v * v;
    }
  }
  #pragma unroll
  for (int j = 0; j < 4; j++) {
    float s = ss[j];
    s += __shfl_xor(s, 1);
    s += __shfl_xor(s, 2);
    s += __shfl_xor(s, 4);
    s += __shfl_xor(s, 8);
    ss[j] = 1.0f / fmaxf(sqrtf(s), 1e-12f);
  }
  #pragma unroll
  for (int ct = 0; ct < 8; ct++) {
    #pragma unroll
    for (int j = 0; j < 4; j++) {
      out[(size_t)(row0 + g * 4 + j) * D + ct * 16 + c0] = acc[ct][j] * ss[j];
    }
  }
}

extern "C" void kernel_launch(void* const* d_in, const int* in_sizes, int n_in,
                              void* d_out, int out_size, void* d_ws, size_t ws_size,
                              hipStream_t stream) {
  const float* x  = (const float*)d_in[0];
  const int*   ei = (const int*)d_in[1];
  const float* Wl = (const float*)d_in[2];
  const float* bl = (const float*)d_in[3];
  const float* Wr = (const float*)d_in[4];
  float* out = (float*)d_out;

  // Workspace layout (int elements)
  int* w = (int*)d_ws;
  int* btail = w;                              // 782 (pad to 800)
  unsigned* part = (unsigned*)(w + 800);       // 782*4096 = 3203072 (12.8 MB)
  unsigned short* wt_g = (unsigned short*)(w + 3203872);  // 32768 u16 = 16384 ints
  const size_t XH_OFF = 3220256ULL * 4;        // bytes, 16B aligned
  const size_t MH_OFF = XH_OFF + (size_t)N_NODES * D * 2;  // +25.6 MB
  unsigned* xh = (unsigned*)((char*)d_ws + XH_OFF);
  unsigned* mh = (unsigned*)((char*)d_ws + MH_OFF);

  hipMemsetAsync(btail, 0, 800 * sizeof(int), stream);
  prepw_k<<<128, 256, 0, stream>>>(Wl, Wr, wt_g);
  cvt_k<<<6250, 256, 0, stream>>>(x, xh);
  p3b_k<<<PBLK, 256, 0, stream>>>(ei, btail, part);
  g3_k<<<NB2, 512, 0, stream>>>(xh, part, btail, mh);
  fused_k<<<(TILES + WPB - 1) / WPB, 512, 0, stream>>>(xh, mh, (const unsigned*)wt_g, bl, out);
}